// Round 9
// baseline (93.904 us; speedup 1.0000x reference)
//
#include <hip/hip_runtime.h>

#define BATCH 8
#define NPTS 9225
#define MQ 4096
#define CAP 64
#define GRID 64
#define NCELLS (GRID * GRID)   // 4096 data cells; window margin 0.00125 vs r=0.03
#define QG 32
#define NQC (QG * QG)          // 1024 query cells per batch (avg 4 queries/cell)
#define STAGE 192              // staged candidates per wave (mean T ~81, sd ~9)

// Unified build: blocks 0..7 = data counting-sort (G64), blocks 8..15 =
// query counting-sort (G32). One dispatch, one block per (kind,batch).
__global__ __launch_bounds__(1024) void build_kernel(
    const float* __restrict__ data, const float* __restrict__ queries,
    int* __restrict__ cell_starts,    // [B][NCELLS+1]
    float4* __restrict__ recs,        // [B][NPTS]  (x,y,idx_bits,0)
    int* __restrict__ qcell_starts,   // [B][NQC+1]
    float4* __restrict__ qrecs) {     // [B][MQ]    (x,y,idx_bits,0)
  __shared__ int hist[NCELLS];
  __shared__ int cursor[NCELLS];
  __shared__ int wavesum[16];
  const int t = threadIdx.x;
  const int lane = t & 63, wid = t >> 6;

  if (blockIdx.x < BATCH) {
    // ---------------- data path (G64) ----------------
    const int b = blockIdx.x;
#pragma unroll
    for (int k = 0; k < NCELLS / 1024; ++k) hist[t + k * 1024] = 0;
    __syncthreads();
    const float2* dp = (const float2*)data + (size_t)b * NPTS;
    for (int i = t; i < NPTS; i += 1024) {
      const float2 p = dp[i];
      const int cx = min(max((int)(p.x * (float)GRID), 0), GRID - 1);
      const int cy = min(max((int)(p.y * (float)GRID), 0), GRID - 1);
      atomicAdd(&hist[cy * GRID + cx], 1);
    }
    __syncthreads();
    const int c0 = hist[4 * t + 0], c1 = hist[4 * t + 1];
    const int c2 = hist[4 * t + 2], c3 = hist[4 * t + 3];
    const int s = c0 + c1 + c2 + c3;
    int v = s;
#pragma unroll
    for (int off = 1; off < 64; off <<= 1) {
      const int u = __shfl_up(v, off, 64);
      if (lane >= off) v += u;
    }
    if (lane == 63) wavesum[wid] = v;
    __syncthreads();
    int woff = 0;
    for (int k = 0; k < wid; ++k) woff += wavesum[k];
    int e = woff + v - s;
    int* cs = cell_starts + b * (NCELLS + 1);
    cs[4 * t + 0] = e; cursor[4 * t + 0] = e; e += c0;
    cs[4 * t + 1] = e; cursor[4 * t + 1] = e; e += c1;
    cs[4 * t + 2] = e; cursor[4 * t + 2] = e; e += c2;
    cs[4 * t + 3] = e; cursor[4 * t + 3] = e; e += c3;
    if (t == 1023) cs[NCELLS] = e;
    __syncthreads();
    float4* rb = recs + (size_t)b * NPTS;
    for (int i = t; i < NPTS; i += 1024) {
      const float2 p = dp[i];
      const int cx = min(max((int)(p.x * (float)GRID), 0), GRID - 1);
      const int cy = min(max((int)(p.y * (float)GRID), 0), GRID - 1);
      const int pos = atomicAdd(&cursor[cy * GRID + cx], 1);
      rb[pos] = make_float4(p.x, p.y, __int_as_float(i), 0.0f);
    }
  } else {
    // ---------------- query path (G32) ----------------
    const int b = blockIdx.x - BATCH;
    hist[t] = 0;
    __syncthreads();
    const float2* qp = (const float2*)queries + (size_t)b * MQ;
#pragma unroll
    for (int k = 0; k < MQ / 1024; ++k) {
      const float2 p = qp[t + k * 1024];
      const int cx = min(max((int)(p.x * (float)QG), 0), QG - 1);
      const int cy = min(max((int)(p.y * (float)QG), 0), QG - 1);
      atomicAdd(&hist[cy * QG + cx], 1);
    }
    __syncthreads();
    const int cval = hist[t];
    int v = cval;
#pragma unroll
    for (int off = 1; off < 64; off <<= 1) {
      const int u = __shfl_up(v, off, 64);
      if (lane >= off) v += u;
    }
    if (lane == 63) wavesum[wid] = v;
    __syncthreads();
    int woff = 0;
    for (int k = 0; k < wid; ++k) woff += wavesum[k];
    const int excl = woff + v - cval;
    int* cs = qcell_starts + b * (NQC + 1);
    cs[t] = excl;
    cursor[t] = excl;
    if (t == NQC - 1) cs[NQC] = excl + cval;
    __syncthreads();
    float4* qr = qrecs + (size_t)b * MQ;
#pragma unroll
    for (int k = 0; k < MQ / 1024; ++k) {
      const int i = t + k * 1024;
      const float2 p = qp[i];
      const int cx = min(max((int)(p.x * (float)QG), 0), QG - 1);
      const int cy = min(max((int)(p.y * (float)QG), 0), QG - 1);
      const int pos = atomicAdd(&cursor[cy * QG + cx], 1);
      qr[pos] = make_float4(p.x, p.y, __int_as_float(i), 0.0f);
    }
  }
}

// One wave per query-cell (avg 4 queries). The 6x6 data-cell union window is
// gathered from global ONCE into LDS; each query re-streams it from LDS.
// No __syncthreads after the divergent early-exit; all LDS use is per-wave.
__global__ __launch_bounds__(256) void search_kernel(
    const float* __restrict__ radius_p,
    const int* __restrict__ cell_starts, const float4* __restrict__ recs,
    const int* __restrict__ qcell_starts, const float4* __restrict__ qrecs,
    int* __restrict__ nbr_idx, int* __restrict__ counts) {
#pragma clang fp contract(off)
  __shared__ float4 stagebuf[4][STAGE];
  __shared__ int hitbuf[4][CAP];
  const int lane = threadIdx.x & 63;
  const int w = threadIdx.x >> 6;
  const int gw = blockIdx.x * 4 + w;
  const int b = gw >> 10;               // NQC = 1024
  const int qc = gw & (NQC - 1);
  const int qs = qcell_starts[b * (NQC + 1) + qc];
  const int qe = qcell_starts[b * (NQC + 1) + qc + 1];
  if (qs == qe) return;                 // empty query cell (~2%)

  const int qcx = qc & (QG - 1), qcy = qc >> 5;
  const int x0 = max(2 * qcx - 2, 0), x1 = min(2 * qcx + 3, GRID - 1);
  const int y0 = max(2 * qcy - 2, 0), y1 = min(2 * qcy + 3, GRID - 1);
  const int csbase = b * (NCELLS + 1);
  int rs[6], rl[6];
#pragma unroll
  for (int i = 0; i < 6; ++i) {
    const int y = y0 + i;
    if (y <= y1) {
      rs[i] = cell_starts[csbase + y * GRID + x0];
      rl[i] = cell_starts[csbase + y * GRID + x1 + 1] - rs[i];
    } else {
      rs[i] = 0; rl[i] = 0;
    }
  }
  const int L0 = rl[0];
  const int L1 = L0 + rl[1];
  const int L2 = L1 + rl[2];
  const int L3 = L2 + rl[3];
  const int L4 = L3 + rl[4];
  const int T = L4 + rl[5];

  const float4* rb = recs + (size_t)b * NPTS;
  // stage up to STAGE candidates into LDS (same-wave write/read: no barrier)
  for (int base = 0; base < T && base < STAGE; base += 64) {
    const int p = base + lane;          // p <= 191 < STAGE
    int i;
    if (p < L0)      i = rs[0] + p;
    else if (p < L1) i = rs[1] + (p - L0);
    else if (p < L2) i = rs[2] + (p - L1);
    else if (p < L3) i = rs[3] + (p - L2);
    else if (p < L4) i = rs[4] + (p - L3);
    else             i = rs[5] + (p - L4);
    if (p >= T) i = 0;
    stagebuf[w][p] = rb[i];
  }

  const unsigned long long below = (1ull << lane) - 1ull;
  const float r = radius_p[0];
  const float r2 = r * r;

  for (int k = qs; k < qe; ++k) {       // wave-uniform query loop
    const float4 qr = qrecs[(size_t)b * MQ + k];
    const float qx = qr.x, qy = qr.y;
    const int qid = __float_as_int(qr.z);
    const float qn = qx * qx + qy * qy;              // mul,mul,add — no fma
    int h = 0;
    for (int base = 0; base < T; base += 64) {
      const int p = base + lane;
      const bool act = (p < T);
      float4 rec;
      if (base < STAGE) {               // wave-uniform branch; hot path
        rec = stagebuf[w][p];
      } else {                          // overflow (T>192): ~never at this density
        int i;
        if (p < L0)      i = rs[0] + p;
        else if (p < L1) i = rs[1] + (p - L0);
        else if (p < L2) i = rs[2] + (p - L1);
        else if (p < L3) i = rs[3] + (p - L2);
        else if (p < L4) i = rs[4] + (p - L3);
        else             i = rs[5] + (p - L4);
        if (!act) i = 0;
        rec = rb[i];
      }
      const float dx = rec.x, dy = rec.y;
      const int id = __float_as_int(rec.z);
      const float dn = dx * dx + dy * dy;            // mul,mul,add — no fma
      const float cross = qx * dx + qy * dy;         // mul,mul,add — no fma
      const float s = (qn + dn) - 2.0f * cross;      // matches np op order
      const bool in = act && (s <= r2);
      const unsigned long long mask = __ballot(in);
      if (in) {
        const int pos = h + __popcll(mask & below);
        if (pos < CAP) hitbuf[w][pos] = id;
      }
      h += __popcll(mask);
    }

    int v = (lane < h && lane < CAP) ? hitbuf[w][lane] : 0x7fffffff;
    // bitonic sort k=2..32 (sorts low 32-half; high half all-MAX when h<=32)
#pragma unroll
    for (int kk = 2; kk <= 32; kk <<= 1) {
#pragma unroll
      for (int j = kk >> 1; j >= 1; j >>= 1) {
        const int other = __shfl_xor(v, j, 64);
        const bool keep_min = (((lane & kk) == 0) == ((lane & j) == 0));
        v = keep_min ? min(v, other) : max(v, other);
      }
    }
    if (h > 32) {
#pragma unroll
      for (int j = 32; j >= 1; j >>= 1) {
        const int other = __shfl_xor(v, j, 64);
        const bool keep_min = ((lane & j) == 0);
        v = keep_min ? min(v, other) : max(v, other);
      }
    }

    const int qglob = b * MQ + qid;
    nbr_idx[(size_t)qglob * CAP + lane] = (v == 0x7fffffff) ? -1 : v;
    if (lane == 0) counts[qglob] = h;
  }
}

// Per-batch exclusive scan of 4096 counts -> row_splits[b][0..4096]
__global__ __launch_bounds__(256) void scan_kernel(const int* __restrict__ counts,
                                                   int* __restrict__ row_splits) {
  const int b = blockIdx.x;
  const int t = threadIdx.x;
  const int PER = MQ / 256;  // 16
  __shared__ int buf[MQ + MQ / 16];
  __shared__ int partial[256];
  const int* c = counts + b * MQ;
#pragma unroll
  for (int k = 0; k < PER; ++k) {
    const int i = t + 256 * k;          // coalesced global read
    buf[i + (i >> 4)] = c[i];
  }
  __syncthreads();
  int local[PER];
  int sum = 0;
#pragma unroll
  for (int k = 0; k < PER; ++k) {
    const int i = t * PER + k;
    local[k] = buf[i + (i >> 4)];
    sum += local[k];
  }
  partial[t] = sum;
  __syncthreads();
  for (int off = 1; off < 256; off <<= 1) {
    int u = (t >= off) ? partial[t - off] : 0;
    __syncthreads();
    partial[t] += u;
    __syncthreads();
  }
  const int excl = (t == 0) ? 0 : partial[t - 1];
  int* rs = row_splits + b * (MQ + 1);
  if (t == 0) rs[0] = 0;
  int run = excl;
#pragma unroll
  for (int k = 0; k < PER; ++k) { run += local[k]; rs[t * PER + k + 1] = run; }
}

extern "C" void kernel_launch(void* const* d_in, const int* in_sizes, int n_in,
                              void* d_out, int out_size, void* d_ws, size_t ws_size,
                              hipStream_t stream) {
  const float* data    = (const float*)d_in[0];
  const float* queries = (const float*)d_in[1];
  const float* radius  = (const float*)d_in[2];
  int* out        = (int*)d_out;
  int* nbr_idx    = out;                       // BATCH*MQ*CAP
  int* row_splits = out + BATCH * MQ * CAP;    // BATCH*(MQ+1)

  // workspace (ints first; int total = 32768+32776+8200 = 73744, 73744*4
  // divisible by 16 -> float4 regions aligned)
  int* counts       = (int*)d_ws;                           // 32768
  int* cell_starts  = counts + BATCH * MQ;                  // 8*4097
  int* qcell_starts = cell_starts + BATCH * (NCELLS + 1);   // 8*1025
  float4* recs      = (float4*)(qcell_starts + BATCH * (NQC + 1));  // 8*9225
  float4* qrecs     = recs + (size_t)BATCH * NPTS;                  // 8*4096

  hipLaunchKernelGGL(build_kernel, dim3(2 * BATCH), dim3(1024), 0, stream,
                     data, queries, cell_starts, recs, qcell_starts, qrecs);
  hipLaunchKernelGGL(search_kernel, dim3(BATCH * NQC / 4), dim3(256), 0, stream,
                     radius, cell_starts, recs, qcell_starts, qrecs,
                     nbr_idx, counts);
  hipLaunchKernelGGL(scan_kernel, dim3(BATCH), dim3(256), 0, stream,
                     counts, row_splits);
}

// Round 10
// 93.351 us; speedup vs baseline: 1.0059x; 1.0059x over previous
//
#include <hip/hip_runtime.h>

#define BATCH 8
#define NPTS 9225
#define MQ 4096
#define CAP 64
#define GRID 96
#define NCELLS (GRID * GRID)   // 9216 cells; window = cx±3, cy±3 (7x7)
// coverage margin: 3/96 = 0.03125 vs r = 0.03 -> 0.00125 slack, identical to
// the R7 (GRID=64, ±2) config that passed with absmax 0. ~49 candidates/query.

__device__ __forceinline__ int cell_of(float x, float y) {
  int cx = (int)(x * (float)GRID);
  int cy = (int)(y * (float)GRID);
  cx = min(max(cx, 0), GRID - 1);
  cy = min(max(cy, 0), GRID - 1);
  return cy * GRID + cx;
}

// One block per batch: LDS histogram (9216 cells, 36.9 KB; cursor reuses the
// hist array to stay under the 64 KB/WG limit) -> 9-cells/thread shfl scan ->
// scatter of merged 16B records (x, y, idx_bits, 0).
__global__ __launch_bounds__(1024) void build_kernel(
    const float* __restrict__ data,
    int* __restrict__ cell_starts,   // [B][NCELLS+1]
    float4* __restrict__ recs) {     // [B][NPTS]
  __shared__ int hist[NCELLS];       // later reused as scatter cursors
  __shared__ int wavesum[16];
  const int b = blockIdx.x;
  const int t = threadIdx.x;
  const int lane = t & 63, wid = t >> 6;
#pragma unroll
  for (int k = 0; k < NCELLS / 1024; ++k) hist[t + k * 1024] = 0;  // 9 exact
  __syncthreads();

  const float2* dp = (const float2*)data + (size_t)b * NPTS;
  for (int i = t; i < NPTS; i += 1024)
    atomicAdd(&hist[cell_of(dp[i].x, dp[i].y)], 1);
  __syncthreads();

  // thread t owns cells [9t, 9t+9)
  int c[9];
  int s = 0;
#pragma unroll
  for (int j = 0; j < 9; ++j) { c[j] = hist[9 * t + j]; s += c[j]; }
  int v = s;
#pragma unroll
  for (int off = 1; off < 64; off <<= 1) {
    const int u = __shfl_up(v, off, 64);
    if (lane >= off) v += u;
  }
  if (lane == 63) wavesum[wid] = v;
  __syncthreads();  // also guarantees all hist reads above are complete
  int woff = 0;
  for (int k = 0; k < wid; ++k) woff += wavesum[k];
  int e = woff + v - s;  // exclusive prefix of cell 9t
  int* cs = cell_starts + b * (NCELLS + 1);
#pragma unroll
  for (int j = 0; j < 9; ++j) {
    cs[9 * t + j] = e;
    hist[9 * t + j] = e;  // hist now serves as the scatter cursor
    e += c[j];
  }
  if (t == 1023) cs[NCELLS] = e;  // == NPTS
  __syncthreads();

  float4* rb = recs + (size_t)b * NPTS;
  for (int i = t; i < NPTS; i += 1024) {
    const float2 p = dp[i];  // re-read (L2 hit)
    const int pos = atomicAdd(&hist[cell_of(p.x, p.y)], 1);
    rb[pos] = make_float4(p.x, p.y, __int_as_float(i), 0.0f);
  }
}

// One wave per query (R7 shape: 4 waves/block, no scalarization); 7 cell-rows
// concatenated into one lane-mapped stream, one 16B record load / candidate.
__global__ __launch_bounds__(256) void search_kernel(
    const float* __restrict__ queries, const float* __restrict__ radius_p,
    const int* __restrict__ cell_starts, const float4* __restrict__ recs,
    int* __restrict__ nbr_idx, int* __restrict__ counts) {
#pragma clang fp contract(off)
  __shared__ int hitbuf[4][CAP];
  const int lane = threadIdx.x & 63;
  const int w = threadIdx.x >> 6;
  const int q = blockIdx.x * 4 + w;     // grid sized exactly
  const int b = q >> 12;                // MQ = 4096
  const float r = radius_p[0];
  const float r2 = r * r;
  const float2 qv = ((const float2*)queries)[q];
  const float qx = qv.x, qy = qv.y;
  const float qn = qx * qx + qy * qy;   // mul,mul,add — no fma (matches np)

  const int cx = min(max((int)(qx * (float)GRID), 0), GRID - 1);
  const int cy = min(max((int)(qy * (float)GRID), 0), GRID - 1);
  const int x0 = max(cx - 3, 0), x1 = min(cx + 3, GRID - 1);
  const int y0 = max(cy - 3, 0), y1 = min(cy + 3, GRID - 1);

  const int csbase = b * (NCELLS + 1);
  int rs[7], rl[7];
#pragma unroll
  for (int i = 0; i < 7; ++i) {
    const int y = y0 + i;
    if (y <= y1) {
      rs[i] = cell_starts[csbase + y * GRID + x0];
      rl[i] = cell_starts[csbase + y * GRID + x1 + 1] - rs[i];
    } else {
      rs[i] = 0; rl[i] = 0;
    }
  }
  const int L0 = rl[0];
  const int L1 = L0 + rl[1];
  const int L2 = L1 + rl[2];
  const int L3 = L2 + rl[3];
  const int L4 = L3 + rl[4];
  const int L5 = L4 + rl[5];
  const int T = L5 + rl[6];

  const unsigned long long below = (1ull << lane) - 1ull;
  const float4* rb = recs + (size_t)b * NPTS;
  int h = 0;

  for (int base = 0; base < T; base += 64) {   // ~1.02 iterations on average
    const int p = base + lane;
    const bool act = (p < T);
    int i;
    if (p < L0)      i = rs[0] + p;
    else if (p < L1) i = rs[1] + (p - L0);
    else if (p < L2) i = rs[2] + (p - L1);
    else if (p < L3) i = rs[3] + (p - L2);
    else if (p < L4) i = rs[4] + (p - L3);
    else if (p < L5) i = rs[5] + (p - L4);
    else             i = rs[6] + (p - L5);
    if (!act) i = 0;  // safe address
    const float4 rec = rb[i];
    const float dx = rec.x, dy = rec.y;
    const int id = __float_as_int(rec.z);
    const float dn = dx * dx + dy * dy;            // mul,mul,add — no fma
    const float cross = qx * dx + qy * dy;         // mul,mul,add — no fma
    const float s = (qn + dn) - 2.0f * cross;      // matches np op order
    const bool in = act && (s <= r2);
    const unsigned long long mask = __ballot(in);
    if (in) {
      const int pos = h + __popcll(mask & below);
      if (pos < CAP) hitbuf[w][pos] = id;
    }
    h += __popcll(mask);
  }

  // gather (same-wave LDS RAW is in-order)
  int v = (lane < h && lane < CAP) ? hitbuf[w][lane] : 0x7fffffff;

  // bitonic sort: k=2..32 sorts each 32-half (high half = all-MAX)
#pragma unroll
  for (int k = 2; k <= 32; k <<= 1) {
#pragma unroll
    for (int j = k >> 1; j >= 1; j >>= 1) {
      const int other = __shfl_xor(v, j, 64);
      const bool keep_min = (((lane & k) == 0) == ((lane & j) == 0));
      v = keep_min ? min(v, other) : max(v, other);
    }
  }
  if (h > 32) {  // final 64-merge only if hits spill past lane 31
#pragma unroll
    for (int j = 32; j >= 1; j >>= 1) {
      const int other = __shfl_xor(v, j, 64);
      const bool keep_min = ((lane & j) == 0);
      v = keep_min ? min(v, other) : max(v, other);
    }
  }

  nbr_idx[(size_t)q * CAP + lane] = (v == 0x7fffffff) ? -1 : v;
  if (lane == 0) counts[q] = h;
}

// Per-batch exclusive scan of 4096 counts -> row_splits[b][0..4096]
__global__ __launch_bounds__(256) void scan_kernel(const int* __restrict__ counts,
                                                   int* __restrict__ row_splits) {
  const int b = blockIdx.x;
  const int t = threadIdx.x;
  const int PER = MQ / 256;  // 16
  __shared__ int partial[256];
  const int* c = counts + b * MQ;
  int local[PER];
  int sum = 0;
#pragma unroll
  for (int k = 0; k < PER; ++k) { local[k] = c[t * PER + k]; sum += local[k]; }
  partial[t] = sum;
  __syncthreads();
  for (int off = 1; off < 256; off <<= 1) {
    int u = (t >= off) ? partial[t - off] : 0;
    __syncthreads();
    partial[t] += u;
    __syncthreads();
  }
  const int excl = (t == 0) ? 0 : partial[t - 1];
  int* rs = row_splits + b * (MQ + 1);
  if (t == 0) rs[0] = 0;
  int run = excl;
#pragma unroll
  for (int k = 0; k < PER; ++k) { run += local[k]; rs[t * PER + k + 1] = run; }
}

extern "C" void kernel_launch(void* const* d_in, const int* in_sizes, int n_in,
                              void* d_out, int out_size, void* d_ws, size_t ws_size,
                              hipStream_t stream) {
  const float* data    = (const float*)d_in[0];
  const float* queries = (const float*)d_in[1];
  const float* radius  = (const float*)d_in[2];
  int* out        = (int*)d_out;
  int* nbr_idx    = out;                       // BATCH*MQ*CAP
  int* row_splits = out + BATCH * MQ * CAP;    // BATCH*(MQ+1)

  // workspace (ints): counts 32768 + cell_starts 8*9217 = 73736 -> 106504
  // ints = 426016 B, divisible by 16 -> recs is 16B-aligned.
  int* counts      = (int*)d_ws;
  int* cell_starts = counts + BATCH * MQ;
  float4* recs     = (float4*)(cell_starts + BATCH * (NCELLS + 1));

  hipLaunchKernelGGL(build_kernel, dim3(BATCH), dim3(1024), 0, stream,
                     data, cell_starts, recs);
  hipLaunchKernelGGL(search_kernel, dim3(BATCH * MQ / 4), dim3(256), 0, stream,
                     queries, radius, cell_starts, recs, nbr_idx, counts);
  hipLaunchKernelGGL(scan_kernel, dim3(BATCH), dim3(256), 0, stream,
                     counts, row_splits);
}